// Round 5
// baseline (575.085 us; speedup 1.0000x reference)
//
#include <hip/hip_runtime.h>

// x:        [B=2, C=16, N=512, Ht=64, Wt=64] float32  (256 MB atlas)
// quad_idx: [Ho=1024, Wo=1024] int32
// tex_uv:   [Ho=1024, Wo=1024, 2] float32
// out:      [B, C, Ho, Wo] float32                    (134 MB)
#define HT 64
#define WT 64
#define NTEX 512
#define HO 1024
#define WO 1024
#define NCH 32
#define SLAB (HT * WT)              // 4096 floats = 16 KB per (channel, texture)
#define NPIX (HO * WO)
#define PXB 4096                    // pixels per prepass block
#define NBLK (NPIX / PXB)           // 256 prepass blocks

typedef float    f32x4 __attribute__((ext_vector_type(4)));
typedef unsigned u32x4 __attribute__((ext_vector_type(4)));

// ---------------- ws layouts (ws proven = 1 GB by harness fills) -------------
// BIG  (>= 16K+141MB):
//   base[513]   @ 0
//   partial     @ 16K        [256][512] u32 (512 KB)  per-block histograms
//   blockbase   @ 16K+512K   [256][512] u32 (512 KB)  per-block placement bases
//   rank_of     @ 16K+1M     (4 MB)
//   meta        @ 16K+5M     (8 MB)   {pix<<12|off, wv16<<16|wu16}
//   compact     @ 16K+13M    (128 MB) [cg8][rank][4ch] f32, 16 B records
// SMALL (>= 16K+10MB): base/partial/blockbase as above, meta @ 16K+1M
#define WS_BASE   0
#define WS_PART   16384
#define WS_BBASE  (16384 + 512 * 1024)
#define MB (1u << 20)
#define WS_RANK   ((size_t)16384 + 1 * MB)
#define WS_METAB  ((size_t)16384 + 5 * MB)
#define WS_CMP    ((size_t)16384 + 13 * MB)
#define WS_METAS  ((size_t)16384 + 1 * MB)
#define WS_NEED_SMALL ((size_t)16384 + 10 * (size_t)MB)
#define WS_NEED_BIG   ((size_t)16384 + 141 * (size_t)MB)

// ---- K1: per-block LDS histogram -> partial[b][bin] (NO global atomics) ----
__global__ __launch_bounds__(256) void k_hist(const int* __restrict__ qi,
                                              unsigned* __restrict__ partial) {
    __shared__ unsigned h[NTEX];
    for (int i = threadIdx.x; i < NTEX; i += 256) h[i] = 0;
    __syncthreads();
    const int p0 = blockIdx.x * PXB;
    for (int k = threadIdx.x; k < PXB; k += 256)
        atomicAdd(&h[qi[p0 + k]], 1u);
    __syncthreads();
    unsigned* row = partial + (size_t)blockIdx.x * NTEX;
    for (int i = threadIdx.x; i < NTEX; i += 256) row[i] = h[i];
}

// ---- K2: column-sum + scan + per-block bases (single block, 512 thr) ----
__global__ __launch_bounds__(512) void k_scan(const unsigned* __restrict__ partial,
                                              unsigned* __restrict__ base,
                                              unsigned* __restrict__ blockbase) {
    __shared__ unsigned t[NTEX];
    const int i = threadIdx.x;            // bin
    unsigned total = 0;
    for (int b = 0; b < NBLK; ++b)        // coalesced: 512 consecutive u32/iter
        total += partial[(size_t)b * NTEX + i];
    t[i] = total;
    __syncthreads();
    for (int s = 1; s < NTEX; s <<= 1) {
        unsigned v = (i >= s) ? t[i - s] : 0u;
        __syncthreads();
        t[i] += v;
        __syncthreads();
    }
    const unsigned excl = t[i] - total;
    base[i] = excl;
    if (i == NTEX - 1) base[NTEX] = t[i];
    unsigned run = excl;
    for (int b = 0; b < NBLK; ++b) {      // coalesced stores
        blockbase[(size_t)b * NTEX + i] = run;
        run += partial[(size_t)b * NTEX + i];
    }
}

// ---- K3: meta build — placement base from blockbase, LDS-only atomics ----
__global__ __launch_bounds__(256) void k_meta(const int* __restrict__ qi,
                                              const float* __restrict__ uvp,
                                              const unsigned* __restrict__ blockbase,
                                              uint2* __restrict__ meta,
                                              unsigned* __restrict__ rank_of) {
    __shared__ unsigned lbase[NTEX];
    __shared__ unsigned lcount[NTEX];
    const int p0 = blockIdx.x * PXB;
    const unsigned* row = blockbase + (size_t)blockIdx.x * NTEX;
    for (int i = threadIdx.x; i < NTEX; i += 256) {
        lbase[i] = row[i];
        lcount[i] = 0;
    }
    __syncthreads();

    for (int k = threadIdx.x; k < PXB; k += 256) {
        const int pix = p0 + k;
        const int n = qi[pix];
        const float2 uv = reinterpret_cast<const float2*>(uvp)[pix];

        const float u = uv.x * (float)(WT - 1);
        const float v = uv.y * (float)(HT - 1);
        int x0 = (int)floorf(u);
        int y0 = (int)floorf(v);
        x0 = min(max(x0, 0), WT - 2);   // x1=x0+1 valid; wu=u-x0 matches ref clamp
        y0 = min(max(y0, 0), HT - 2);
        const float wu = u - (float)x0;
        const float wv = v - (float)y0;

        const unsigned off  = (unsigned)(y0 * WT + x0);          // 12 bits
        const unsigned key  = ((unsigned)pix << 12) | off;
        const unsigned wu16 = (unsigned)__float2int_rn(wu * 65535.0f);
        const unsigned wv16 = (unsigned)__float2int_rn(wv * 65535.0f);

        const unsigned rank = lbase[n] + atomicAdd(&lcount[n], 1u);
        meta[rank] = make_uint2(key, wu16 | (wv16 << 16));
        if (rank_of) rank_of[pix] = rank;
    }
}

// ---- K4-BIG: (texture, 4-channel group) -> compact[cg][rank][4] ----
// 64 KB LDS -> 2 blocks/CU (stage/compute overlap across blocks).
// Same-texture cg-blocks are 512 apart -> same XCD -> meta bucket L2-reuse.
__global__ __launch_bounds__(512) void k_gather4(const float* __restrict__ x,
                                                 const unsigned* __restrict__ base,
                                                 const uint2* __restrict__ meta,
                                                 float* __restrict__ compact) {
    __shared__ float s[4 * SLAB];    // 64 KB
    const int b = blockIdx.x;        // 0..4095
    const int n = b & 511;           // texture
    const int cg = b >> 9;           // channel group 0..7 (4 channels each)
    const int tid = threadIdx.x;

    #pragma unroll
    for (int ch = 0; ch < 4; ++ch) {
        const f32x4* __restrict__ src = reinterpret_cast<const f32x4*>(
            x + ((size_t)(cg * 4 + ch) * NTEX + n) * SLAB);
        f32x4* d = reinterpret_cast<f32x4*>(s + ch * SLAB);
        d[tid]       = src[tid];
        d[tid + 512] = src[tid + 512];
    }
    __syncthreads();

    const unsigned lo = base[n];
    const unsigned cnt = base[n + 1] - lo;
    const uint2* __restrict__ m = meta + lo;
    f32x4* __restrict__ cc =
        reinterpret_cast<f32x4*>(compact) + (size_t)cg * NPIX + lo;

    for (unsigned j = tid; j < cnt; j += 512) {
        const uint2 r = m[j];
        const unsigned off = r.x & 4095u;
        const float wu = (float)(r.y & 65535u) * (1.0f / 65535.0f);
        const float wv = (float)(r.y >> 16) * (1.0f / 65535.0f);

        f32x4 o;
        #pragma unroll
        for (int ch = 0; ch < 4; ++ch) {
            const float* __restrict__ sc = s + ch * SLAB + off;
            const float g00 = sc[0];
            const float g01 = sc[1];
            const float g10 = sc[WT];
            const float g11 = sc[WT + 1];
            const float top = g00 + wu * (g01 - g00);
            const float bot = g10 + wu * (g11 - g10);
            o[ch] = top + wv * (bot - top);
        }
        __builtin_nontemporal_store(o, cc + j);
    }
}

// ---- K5-BIG: permutation, 4 px/thread: 16.2 mem-requests per pixel ----
// 1 u32x4 rank load + 32 x 16 B gathers (full-line with L3 reuse) +
// 32 x 16 B coalesced NT stores. Register px<->ch transpose, static idx only.
__global__ __launch_bounds__(256) void k_scatter4(const unsigned* __restrict__ rank_of,
                                                  const float* __restrict__ compact,
                                                  float* __restrict__ out) {
    const int t = threadIdx.x;
    const int P = blockIdx.x * 1024;           // 1024 px per block
    const u32x4 r4 =
        *reinterpret_cast<const u32x4*>(rank_of + P + 4 * t);
    const f32x4* __restrict__ cp = reinterpret_cast<const f32x4*>(compact);

    f32x4 v[8][4];                              // [cg][px] -> 4 ch each
    #pragma unroll
    for (int cg = 0; cg < 8; ++cg) {
        #pragma unroll
        for (int k = 0; k < 4; ++k)
            v[cg][k] = cp[(size_t)cg * NPIX + r4[k]];
    }

    float* __restrict__ o = out + P + 4 * t;
    #pragma unroll
    for (int cg = 0; cg < 8; ++cg) {
        #pragma unroll
        for (int kc = 0; kc < 4; ++kc) {
            f32x4 w;
            w.x = v[cg][0][kc];
            w.y = v[cg][1][kc];
            w.z = v[cg][2][kc];
            w.w = v[cg][3][kc];
            __builtin_nontemporal_store(w,
                reinterpret_cast<f32x4*>(o + (size_t)(cg * 4 + kc) * NPIX));
        }
    }
}

// ---- K4-SMALL: scatter k_main (round-0 style) ----
__global__ __launch_bounds__(256) void k_main(const float* __restrict__ x,
                                              const unsigned* __restrict__ base,
                                              const uint2* __restrict__ meta,
                                              float* __restrict__ out) {
    __shared__ float s[SLAB];

    const int b = blockIdx.x;
    const int xcd = b & 7;
    const int i = b >> 3;
    const int cgrp = i >> 9;
    const int n = i & 511;
    const int c = cgrp * 8 + xcd;

    const f32x4* __restrict__ slab4 =
        reinterpret_cast<const f32x4*>(x + ((size_t)c * NTEX + n) * SLAB);
    f32x4* s4 = reinterpret_cast<f32x4*>(s);
    #pragma unroll
    for (int j = 0; j < 4; ++j)
        s4[threadIdx.x + 256 * j] = slab4[threadIdx.x + 256 * j];
    __syncthreads();

    const unsigned lo = base[n];
    const unsigned cnt = base[n + 1] - lo;
    const uint2* __restrict__ m = meta + lo;
    float* __restrict__ o = out + (size_t)c * NPIX;

    for (unsigned j = threadIdx.x; j < cnt; j += 256) {
        const uint2 r = m[j];
        const unsigned off = r.x & 4095u;
        const unsigned pix = r.x >> 12;
        const float wu = (float)(r.y & 65535u) * (1.0f / 65535.0f);
        const float wv = (float)(r.y >> 16) * (1.0f / 65535.0f);

        const float g00 = s[off];
        const float g01 = s[off + 1];
        const float g10 = s[off + WT];
        const float g11 = s[off + WT + 1];

        const float top = g00 + wu * (g01 - g00);
        const float bot = g10 + wu * (g11 - g10);
        o[pix] = top + wv * (bot - top);
    }
}

// ---- fallback if ws tiny ----
__global__ __launch_bounds__(256) void k_direct(const float* __restrict__ x,
                                                const int* __restrict__ quad_idx,
                                                const float* __restrict__ tex_uv,
                                                float* __restrict__ out) {
    const int pix = blockIdx.x * blockDim.x + threadIdx.x;
    const int chunk = blockIdx.y;
    const int n = quad_idx[pix];
    const float2 uv = reinterpret_cast<const float2*>(tex_uv)[pix];
    const float u = uv.x * (float)(WT - 1);
    const float v = uv.y * (float)(HT - 1);
    int x0 = (int)floorf(u), y0 = (int)floorf(v);
    x0 = min(max(x0, 0), WT - 2);
    y0 = min(max(y0, 0), HT - 2);
    const float wu = u - (float)x0, wv = v - (float)y0;
    const float w00 = (1.f - wu) * (1.f - wv), w01 = wu * (1.f - wv);
    const float w10 = (1.f - wu) * wv, w11 = wu * wv;
    const int off0 = n * SLAB + y0 * WT + x0, off1 = off0 + WT;
    const float* p = x + (size_t)chunk * 8 * NTEX * SLAB;
    float* o = out + (size_t)chunk * 8 * NPIX + pix;
    #pragma unroll
    for (int ch = 0; ch < 8; ++ch) {
        float2 r0, r1;
        __builtin_memcpy(&r0, p + off0, 8);
        __builtin_memcpy(&r1, p + off1, 8);
        o[0] = w00 * r0.x + w01 * r0.y + w10 * r1.x + w11 * r1.y;
        p += (size_t)NTEX * SLAB;
        o += NPIX;
    }
}

extern "C" void kernel_launch(void* const* d_in, const int* in_sizes, int n_in,
                              void* d_out, int out_size, void* d_ws, size_t ws_size,
                              hipStream_t stream) {
    const float* x        = (const float*)d_in[0];
    const int*   quad_idx = (const int*)d_in[1];
    const float* tex_uv   = (const float*)d_in[2];
    float*       out      = (float*)d_out;
    char* ws = (char*)d_ws;

    if (ws_size >= WS_NEED_BIG) {
        unsigned* base      = (unsigned*)(ws + WS_BASE);
        unsigned* partial   = (unsigned*)(ws + WS_PART);
        unsigned* blockbase = (unsigned*)(ws + WS_BBASE);
        unsigned* rank_of   = (unsigned*)(ws + WS_RANK);
        uint2*    meta      = (uint2*)(ws + WS_METAB);
        float*    compact   = (float*)(ws + WS_CMP);

        k_hist<<<NBLK, 256, 0, stream>>>(quad_idx, partial);
        k_scan<<<1, 512, 0, stream>>>(partial, base, blockbase);
        k_meta<<<NBLK, 256, 0, stream>>>(quad_idx, tex_uv, blockbase,
                                         meta, rank_of);
        k_gather4<<<NTEX * 8, 512, 0, stream>>>(x, base, meta, compact);
        k_scatter4<<<NPIX / 1024, 256, 0, stream>>>(rank_of, compact, out);
    } else if (ws_size >= WS_NEED_SMALL) {
        unsigned* base      = (unsigned*)(ws + WS_BASE);
        unsigned* partial   = (unsigned*)(ws + WS_PART);
        unsigned* blockbase = (unsigned*)(ws + WS_BBASE);
        uint2*    meta      = (uint2*)(ws + WS_METAS);

        k_hist<<<NBLK, 256, 0, stream>>>(quad_idx, partial);
        k_scan<<<1, 512, 0, stream>>>(partial, base, blockbase);
        k_meta<<<NBLK, 256, 0, stream>>>(quad_idx, tex_uv, blockbase,
                                         meta, (unsigned*)nullptr);
        k_main<<<NTEX * NCH, 256, 0, stream>>>(x, base, meta, out);
    } else {
        dim3 grid(NPIX / 256, 4);
        k_direct<<<grid, 256, 0, stream>>>(x, quad_idx, tex_uv, out);
    }
}

// Round 6
// 562.388 us; speedup vs baseline: 1.0226x; 1.0226x over previous
//
#include <hip/hip_runtime.h>

// x:        [B=2, C=16, N=512, Ht=64, Wt=64] float32  (256 MB atlas)
// quad_idx: [Ho=1024, Wo=1024] int32
// tex_uv:   [Ho=1024, Wo=1024, 2] float32
// out:      [B, C, Ho, Wo] float32                    (134 MB)
#define HT 64
#define WT 64
#define NTEX 512
#define HO 1024
#define WO 1024
#define NCH 32
#define SLAB (HT * WT)              // 4096 floats = 16 KB per (channel, texture)
#define NPIX (HO * WO)
#define PXB 4096                    // pixels per prepass block
#define NBLK (NPIX / PXB)           // 256 prepass blocks

typedef float    f32x4 __attribute__((ext_vector_type(4)));
typedef float    f32x8 __attribute__((ext_vector_type(8)));
typedef unsigned u32x4 __attribute__((ext_vector_type(4)));

// ---------------- ws layouts (harness ws proven 1 GB) ------------------------
// BIG (>= 16K+141MB):
//   base[513] @ 0 ; partial [256][512] u32 @ 16K (512 KB) ;
//   rank_of @ 16K+1M (4 MB) ; meta @ 16K+5M (8 MB) ;
//   compact @ 16K+13M (128 MB) layout [cg4][rank][8ch] f32 (32 B records)
// SMALL (>= 16K+10MB): as above but meta @ 16K+1M, no rank_of/compact
#define WS_BASE   0
#define WS_PART   16384
#define MB (1u << 20)
#define WS_RANK   ((size_t)16384 + 1 * MB)
#define WS_METAB  ((size_t)16384 + 5 * MB)
#define WS_CMP    ((size_t)16384 + 13 * MB)
#define WS_METAS  ((size_t)16384 + 1 * MB)
#define WS_NEED_SMALL ((size_t)16384 + 10 * (size_t)MB)
#define WS_NEED_BIG   ((size_t)16384 + 141 * (size_t)MB)

// ---- K1: per-block LDS histogram -> partial[b][bin] (no global atomics) ----
__global__ __launch_bounds__(256) void k_hist(const int* __restrict__ qi,
                                              unsigned* __restrict__ partial) {
    __shared__ unsigned h[NTEX];
    for (int i = threadIdx.x; i < NTEX; i += 256) h[i] = 0;
    __syncthreads();
    const int p0 = blockIdx.x * PXB;
    for (int k = threadIdx.x; k < PXB; k += 256)
        atomicAdd(&h[qi[p0 + k]], 1u);
    __syncthreads();
    unsigned* row = partial + (size_t)blockIdx.x * NTEX;
    for (int i = threadIdx.x; i < NTEX; i += 256) row[i] = h[i];
}

// ---- K2: bin totals (coalesced strided sum) + 512-bin exclusive scan ----
__global__ __launch_bounds__(512) void k_scan(const unsigned* __restrict__ partial,
                                              unsigned* __restrict__ base) {
    __shared__ unsigned t[NTEX];
    const int i = threadIdx.x;
    unsigned total = 0;
    for (int b = 0; b < NBLK; ++b)        // per-b: 2 KB contiguous across waves
        total += partial[(size_t)b * NTEX + i];
    t[i] = total;
    __syncthreads();
    for (int s = 1; s < NTEX; s <<= 1) {
        unsigned v = (i >= s) ? t[i - s] : 0u;
        __syncthreads();
        t[i] += v;
        __syncthreads();
    }
    base[i] = t[i] - total;
    if (i == NTEX - 1) base[NTEX] = t[i];
}

// ---- K3: meta build; per-block base computed locally (parallel prefix) ----
__global__ __launch_bounds__(256) void k_meta(const int* __restrict__ qi,
                                              const float* __restrict__ uvp,
                                              const unsigned* __restrict__ partial,
                                              const unsigned* __restrict__ base,
                                              uint2* __restrict__ meta,
                                              unsigned* __restrict__ rank_of) {
    __shared__ unsigned lbase[NTEX];
    __shared__ unsigned lcount[NTEX];
    const int tid = threadIdx.x;
    const int p0 = blockIdx.x * PXB;

    // prefix over earlier blocks' histograms: coalesced, fully parallel
    unsigned acc0 = 0, acc1 = 0;
    for (int b2 = 0; b2 < blockIdx.x; ++b2) {
        const unsigned* row = partial + (size_t)b2 * NTEX;
        acc0 += row[tid];
        acc1 += row[tid + 256];
    }
    lbase[tid]       = base[tid] + acc0;
    lbase[tid + 256] = base[tid + 256] + acc1;
    lcount[tid] = 0;
    lcount[tid + 256] = 0;
    __syncthreads();

    for (int k = tid; k < PXB; k += 256) {
        const int pix = p0 + k;
        const int n = qi[pix];
        const float2 uv = reinterpret_cast<const float2*>(uvp)[pix];

        const float u = uv.x * (float)(WT - 1);
        const float v = uv.y * (float)(HT - 1);
        int x0 = (int)floorf(u);
        int y0 = (int)floorf(v);
        x0 = min(max(x0, 0), WT - 2);   // x1=x0+1 valid; wu=u-x0 matches ref clamp
        y0 = min(max(y0, 0), HT - 2);
        const float wu = u - (float)x0;
        const float wv = v - (float)y0;

        const unsigned off  = (unsigned)(y0 * WT + x0);          // 12 bits
        const unsigned key  = ((unsigned)pix << 12) | off;
        const unsigned wu16 = (unsigned)__float2int_rn(wu * 65535.0f);
        const unsigned wv16 = (unsigned)__float2int_rn(wv * 65535.0f);

        const unsigned rank = lbase[n] + atomicAdd(&lcount[n], 1u);
        meta[rank] = make_uint2(key, wu16 | (wv16 << 16));
        if (rank_of) rank_of[pix] = rank;
    }
}

// ---- K4-BIG: (texture, 8-channel group) -> compact[cg][rank][8]  ----
// Round-4 structure (555 µs build): 128 KB LDS, 32 B records -> best
// scatter-side line utilization. Same-texture cg-blocks on same XCD (b%8=n%8)
// -> meta bucket L2 reuse.
__global__ __launch_bounds__(512) void k_gather8(const float* __restrict__ x,
                                                 const unsigned* __restrict__ base,
                                                 const uint2* __restrict__ meta,
                                                 float* __restrict__ compact) {
    __shared__ float s[8 * SLAB];    // 128 KB
    const int b = blockIdx.x;        // 0..2047
    const int n = b & 511;           // texture
    const int cg = b >> 9;           // channel group 0..3
    const int tid = threadIdx.x;

    #pragma unroll
    for (int ch = 0; ch < 8; ++ch) {
        const f32x4* __restrict__ src = reinterpret_cast<const f32x4*>(
            x + ((size_t)(cg * 8 + ch) * NTEX + n) * SLAB);
        f32x4* d = reinterpret_cast<f32x4*>(s + ch * SLAB);
        d[tid]       = src[tid];
        d[tid + 512] = src[tid + 512];
    }
    __syncthreads();

    const unsigned lo = base[n];
    const unsigned cnt = base[n + 1] - lo;
    const uint2* __restrict__ m = meta + lo;
    float* __restrict__ cc = compact + ((size_t)cg * NPIX + lo) * 8;

    for (unsigned j = tid; j < cnt; j += 512) {
        const uint2 r = m[j];
        const unsigned off = r.x & 4095u;
        const float wu = (float)(r.y & 65535u) * (1.0f / 65535.0f);
        const float wv = (float)(r.y >> 16) * (1.0f / 65535.0f);

        f32x8 o;
        #pragma unroll
        for (int ch = 0; ch < 8; ++ch) {
            const float* __restrict__ sc = s + ch * SLAB + off;
            const float g00 = sc[0];
            const float g01 = sc[1];
            const float g10 = sc[WT];
            const float g11 = sc[WT + 1];
            const float top = g00 + wu * (g01 - g00);
            const float bot = g10 + wu * (g11 - g10);
            o[ch] = top + wv * (bot - top);
        }
        __builtin_nontemporal_store(o,
            reinterpret_cast<f32x8*>(cc + (size_t)j * 8));
    }
}

// ---- K5-BIG: permutation, 4 px/thread, streamed per cg-plane ----
// Loads: full-sector f32x8 (4 line-touches/px, 2 records/line L3 reuse);
// stores: 32 coalesced NT f32x4 (8/px). Live set ~4 x f32x8 -> low VGPR,
// full occupancy. All vector subscripts unrolled (no scratch).
__global__ __launch_bounds__(256) void k_scatter(const unsigned* __restrict__ rank_of,
                                                 const float* __restrict__ compact,
                                                 float* __restrict__ out) {
    const int t = threadIdx.x;
    const int P = blockIdx.x * 1024;           // 1024 px per block
    const u32x4 r4 = *reinterpret_cast<const u32x4*>(rank_of + P + 4 * t);
    const f32x8* __restrict__ cp = reinterpret_cast<const f32x8*>(compact);
    float* __restrict__ o = out + P + 4 * t;

    #pragma unroll
    for (int cg = 0; cg < 4; ++cg) {
        f32x8 a0 = cp[(size_t)cg * NPIX + r4[0]];
        f32x8 a1 = cp[(size_t)cg * NPIX + r4[1]];
        f32x8 a2 = cp[(size_t)cg * NPIX + r4[2]];
        f32x8 a3 = cp[(size_t)cg * NPIX + r4[3]];
        #pragma unroll
        for (int ch = 0; ch < 8; ++ch) {
            f32x4 w;
            w.x = a0[ch];
            w.y = a1[ch];
            w.z = a2[ch];
            w.w = a3[ch];
            __builtin_nontemporal_store(w,
                reinterpret_cast<f32x4*>(o + (size_t)(cg * 8 + ch) * NPIX));
        }
    }
}

// ---- K4-SMALL: scatter k_main (round-0 style) ----
__global__ __launch_bounds__(256) void k_main(const float* __restrict__ x,
                                              const unsigned* __restrict__ base,
                                              const uint2* __restrict__ meta,
                                              float* __restrict__ out) {
    __shared__ float s[SLAB];

    const int b = blockIdx.x;
    const int xcd = b & 7;
    const int i = b >> 3;
    const int cgrp = i >> 9;
    const int n = i & 511;
    const int c = cgrp * 8 + xcd;

    const f32x4* __restrict__ slab4 =
        reinterpret_cast<const f32x4*>(x + ((size_t)c * NTEX + n) * SLAB);
    f32x4* s4 = reinterpret_cast<f32x4*>(s);
    #pragma unroll
    for (int j = 0; j < 4; ++j)
        s4[threadIdx.x + 256 * j] = slab4[threadIdx.x + 256 * j];
    __syncthreads();

    const unsigned lo = base[n];
    const unsigned cnt = base[n + 1] - lo;
    const uint2* __restrict__ m = meta + lo;
    float* __restrict__ o = out + (size_t)c * NPIX;

    for (unsigned j = threadIdx.x; j < cnt; j += 256) {
        const uint2 r = m[j];
        const unsigned off = r.x & 4095u;
        const unsigned pix = r.x >> 12;
        const float wu = (float)(r.y & 65535u) * (1.0f / 65535.0f);
        const float wv = (float)(r.y >> 16) * (1.0f / 65535.0f);

        const float g00 = s[off];
        const float g01 = s[off + 1];
        const float g10 = s[off + WT];
        const float g11 = s[off + WT + 1];

        const float top = g00 + wu * (g01 - g00);
        const float bot = g10 + wu * (g11 - g10);
        o[pix] = top + wv * (bot - top);
    }
}

// ---- fallback if ws tiny ----
__global__ __launch_bounds__(256) void k_direct(const float* __restrict__ x,
                                                const int* __restrict__ quad_idx,
                                                const float* __restrict__ tex_uv,
                                                float* __restrict__ out) {
    const int pix = blockIdx.x * blockDim.x + threadIdx.x;
    const int chunk = blockIdx.y;
    const int n = quad_idx[pix];
    const float2 uv = reinterpret_cast<const float2*>(tex_uv)[pix];
    const float u = uv.x * (float)(WT - 1);
    const float v = uv.y * (float)(HT - 1);
    int x0 = (int)floorf(u), y0 = (int)floorf(v);
    x0 = min(max(x0, 0), WT - 2);
    y0 = min(max(y0, 0), HT - 2);
    const float wu = u - (float)x0, wv = v - (float)y0;
    const float w00 = (1.f - wu) * (1.f - wv), w01 = wu * (1.f - wv);
    const float w10 = (1.f - wu) * wv, w11 = wu * wv;
    const int off0 = n * SLAB + y0 * WT + x0, off1 = off0 + WT;
    const float* p = x + (size_t)chunk * 8 * NTEX * SLAB;
    float* o = out + (size_t)chunk * 8 * NPIX + pix;
    #pragma unroll
    for (int ch = 0; ch < 8; ++ch) {
        float2 r0, r1;
        __builtin_memcpy(&r0, p + off0, 8);
        __builtin_memcpy(&r1, p + off1, 8);
        o[0] = w00 * r0.x + w01 * r0.y + w10 * r1.x + w11 * r1.y;
        p += (size_t)NTEX * SLAB;
        o += NPIX;
    }
}

extern "C" void kernel_launch(void* const* d_in, const int* in_sizes, int n_in,
                              void* d_out, int out_size, void* d_ws, size_t ws_size,
                              hipStream_t stream) {
    const float* x        = (const float*)d_in[0];
    const int*   quad_idx = (const int*)d_in[1];
    const float* tex_uv   = (const float*)d_in[2];
    float*       out      = (float*)d_out;
    char* ws = (char*)d_ws;

    if (ws_size >= WS_NEED_BIG) {
        unsigned* base    = (unsigned*)(ws + WS_BASE);
        unsigned* partial = (unsigned*)(ws + WS_PART);
        unsigned* rank_of = (unsigned*)(ws + WS_RANK);
        uint2*    meta    = (uint2*)(ws + WS_METAB);
        float*    compact = (float*)(ws + WS_CMP);

        k_hist<<<NBLK, 256, 0, stream>>>(quad_idx, partial);
        k_scan<<<1, 512, 0, stream>>>(partial, base);
        k_meta<<<NBLK, 256, 0, stream>>>(quad_idx, tex_uv, partial, base,
                                         meta, rank_of);
        k_gather8<<<NTEX * 4, 512, 0, stream>>>(x, base, meta, compact);
        k_scatter<<<NPIX / 1024, 256, 0, stream>>>(rank_of, compact, out);
    } else if (ws_size >= WS_NEED_SMALL) {
        unsigned* base    = (unsigned*)(ws + WS_BASE);
        unsigned* partial = (unsigned*)(ws + WS_PART);
        uint2*    meta    = (uint2*)(ws + WS_METAS);

        k_hist<<<NBLK, 256, 0, stream>>>(quad_idx, partial);
        k_scan<<<1, 512, 0, stream>>>(partial, base);
        k_meta<<<NBLK, 256, 0, stream>>>(quad_idx, tex_uv, partial, base,
                                         meta, (unsigned*)nullptr);
        k_main<<<NTEX * NCH, 256, 0, stream>>>(x, base, meta, out);
    } else {
        dim3 grid(NPIX / 256, 4);
        k_direct<<<grid, 256, 0, stream>>>(x, quad_idx, tex_uv, out);
    }
}